// Round 8
// baseline (482.722 us; speedup 1.0000x reference)
//
#include <hip/hip_runtime.h>
#include <math.h>

#define BLOCK 512
#define ROWS 8

typedef __attribute__((ext_vector_type(8))) short s16x8;
typedef __attribute__((ext_vector_type(4))) float f32x4;

// ---- LDS layout (dword offsets) ----
static constexpr int O_H1   = 0;      // bf16 [16][136] = 1088 dw (shared)
static constexpr int O_SU   = 1088;   // f32 [8][260]   = 2080 dw (shared, RO)
static constexpr int O_PP   = 3168;   // f32 [8 waves][8 col][8 row] = 512 dw (L3 partials)
static constexpr int O_PRIV = 3680;   // per wave: inh bf16[16][72]=576dw + xm f32[64]
static constexpr int PRIV_DW = 640;
static constexpr int LDSN   = O_PRIV + 8 * PRIV_DW;   // 8800 dw = 35200 B

__device__ __forceinline__ unsigned short f2bf(float f) {  // fp32->bf16 RNE
  unsigned u = __float_as_uint(f);
  return (unsigned short)((u + 0x7fffu + ((u >> 16) & 1u)) >> 16);
}
__device__ __forceinline__ unsigned cvt_pk_bf16(float lo, float hi) {
  unsigned r;
  asm("v_cvt_pk_bf16_f32 %0, %1, %2" : "=v"(r) : "v"(lo), "v"(hi));
  return r;
}
// tanh(x) = 1 - 2/(exp2(2*log2e*x)+1); saturates correctly at +/-inf
__device__ __forceinline__ float tanh_fast(float x) {
  float e = __builtin_amdgcn_exp2f(x * 2.88539008177792681f);
  return fmaf(-2.f, __builtin_amdgcn_rcpf(e + 1.f), 1.f);
}

#define MFMA16(A, B, C) __builtin_amdgcn_mfma_f32_16x16x32_bf16((A), (B), (C), 0, 0, 0)

extern "C" __global__ void __launch_bounds__(BLOCK, 1)
cstr_rk4_mfma8(const float* __restrict__ useq, const float* __restrict__ xGz0,
               const float* __restrict__ W1, const float* __restrict__ b1,
               const float* __restrict__ W2, const float* __restrict__ b2,
               const float* __restrict__ W3, const float* __restrict__ b3,
               float* __restrict__ out)
{
  extern __shared__ float smf[];
  unsigned short* h1h = (unsigned short*)(smf + O_H1);
  unsigned*       h1u = (unsigned*)(smf + O_H1);
  float* su = smf + O_SU;   // [8][260]
  float* pp = smf + O_PP;   // [8][8][8]

  const int tid  = threadIdx.x;
  const int w    = tid >> 6;     // wave 0..7 (owns m-block w)
  const int l    = tid & 63;
  const int nn   = l & 15;       // frag col (batch row)
  const int hh   = l >> 4;       // k-quarter
  const int r    = l >> 3;       // state row  (0..7)
  const int c    = l & 7;        // state comp (0..7)
  const int base = blockIdx.x * ROWS;

  float* wp_ = smf + O_PRIV + w * PRIV_DW;
  unsigned short* inhp = (unsigned short*)wp_;   // private [16][72] bf16
  float* xmp = wp_ + 576;                        // private [8][8] f32

  // ---------- staging ----------
  for (int i = tid; i < 8 * 260; i += BLOCK) {
    int row = i / 260, col = i % 260;
    su[i] = (col < 256) ? useq[(size_t)base * 256 + row * 256 + col] : 0.f;
  }
  for (int i = l; i < 16 * 72; i += 64) {        // each wave stages its own copy
    int n_ = i / 72, k = i % 72;
    unsigned short v = 0;
    if (n_ < ROWS) {
      if (k < 58)      v = f2bf(xGz0[(size_t)(base + n_) * 58 + k]);
      else if (k < 60) v = f2bf(useq[(size_t)(base + n_) * 256 + (k - 58)]);
    }
    inhp[i] = v;
  }
  xmp[l] = xGz0[(size_t)(base + r) * 58 + c];

  // ---------- per-lane state registers (replicated per wave) ----------
  const size_t rowb = (size_t)(base + r) * 58;
  float xg  = xGz0[rowb + c];
  float yp0 = xGz0[rowb + 8 + c],  yp1 = xGz0[rowb + 16 + c];
  float yp2 = xGz0[rowb + 24 + c], yp3 = xGz0[rowb + 32 + c];
  float yp4 = xGz0[rowb + 40 + c];
  float upA = xGz0[rowb + 48 + c];
  float upB = (c < 2) ? xGz0[rowb + 56 + c] : 0.f;
  float b3r = b3[c];
  float kacc = 0.f;

  // ---------- weights -> VGPR fragments (direct from global, one-time) ----------
  const int j = 16 * w + nn;
  s16x8 a10, a11, a20, a21, a22, a23, a3h;
  #pragma unroll
  for (int i = 0; i < 8; ++i) {
    int k0 = 8 * hh + i, k1 = 32 + 8 * hh + i;
    a10[i] = (short)f2bf(W1[k0 * 128 + j]);
    a11[i] = (short)((k1 < 60) ? f2bf(W1[k1 * 128 + j]) : 0);
    a20[i] = (short)f2bf(W2[(     8 * hh + i) * 128 + j]);
    a21[i] = (short)f2bf(W2[(32 + 8 * hh + i) * 128 + j]);
    a22[i] = (short)f2bf(W2[(64 + 8 * hh + i) * 128 + j]);
    a23[i] = (short)f2bf(W2[(96 + 8 * hh + i) * 128 + j]);
    // L3 A-frag: k-slice of THIS wave's m-block, elements 0..3 only (4..7 = 0).
    // element i<4 pairs with B-frag element i = tanh(c2[i]) = neuron 16w+4hh+i.
    unsigned short z = 0;
    if (i < 4 && nn < 8) z = f2bf(W3[(16 * w + 4 * hh + i) * 8 + nn]);
    a3h[i] = (short)z;
  }
  const float4 bva = *(const float4*)(b1 + 16 * w + 4 * hh);
  const float4 bvb = *(const float4*)(b2 + 16 * w + 4 * hh);

  __syncthreads();

  // ================= main loop =================
  #pragma unroll 1
  for (int t = 0; t < 128; ++t) {
    const float u0r = su[r * 260 + 2 * t];
    const float u1r = su[r * 260 + 2 * t + 1];
    if (w == 0) out[((size_t)(base + r) * 128 + t) * 8 + c] = xg;   // y_t = xG

    #pragma unroll
    for (int s = 0; s < 4; ++s) {
      // ---------- A: L1, m-block w (private inh; same-wave dep only) ----------
      {
        s16x8 bb0 = *(const s16x8*)(inhp + nn * 72 + 8 * hh);
        s16x8 bb1 = *(const s16x8*)(inhp + nn * 72 + 32 + 8 * hh);
        f32x4 c1 = (f32x4){0.f, 0.f, 0.f, 0.f};
        c1 = MFMA16(a10, bb0, c1);
        c1 = MFMA16(a11, bb1, c1);
        float t0 = tanh_fast(c1[0] + bva.x);
        float t1 = tanh_fast(c1[1] + bva.y);
        float t2 = tanh_fast(c1[2] + bva.z);
        float t3 = tanh_fast(c1[3] + bva.w);
        uint2 pk; pk.x = cvt_pk_bf16(t0, t1); pk.y = cvt_pk_bf16(t2, t3);
        *(uint2*)(h1u + nn * 68 + 8 * w + 2 * hh) = pk;
      }
      __syncthreads();   // h1 complete

      // ---------- B: L2 (full K=128) + in-register L3 partial ----------
      {
        const unsigned short* h1row = h1h + nn * 136;
        s16x8 q0 = *(const s16x8*)(h1row +  0 + 8 * hh);
        s16x8 q1 = *(const s16x8*)(h1row + 32 + 8 * hh);
        s16x8 q2 = *(const s16x8*)(h1row + 64 + 8 * hh);
        s16x8 q3 = *(const s16x8*)(h1row + 96 + 8 * hh);
        f32x4 c2 = (f32x4){0.f, 0.f, 0.f, 0.f};
        c2 = MFMA16(a20, q0, c2); c2 = MFMA16(a21, q1, c2);
        c2 = MFMA16(a22, q2, c2); c2 = MFMA16(a23, q3, c2);
        float t0 = tanh_fast(c2[0] + bvb.x);
        float t1 = tanh_fast(c2[1] + bvb.y);
        float t2 = tanh_fast(c2[2] + bvb.z);
        float t3 = tanh_fast(c2[3] + bvb.w);
        // B-frag for L3: elements 0..3 = tanh values (rows 4hh+i of m-block w),
        // elements 4..7 = 0 (paired with zeroed A elements -> contribute 0).
        s16x8 bf3;
        ((unsigned*)&bf3)[0] = cvt_pk_bf16(t0, t1);
        ((unsigned*)&bf3)[1] = cvt_pk_bf16(t2, t3);
        ((unsigned*)&bf3)[2] = 0u;
        ((unsigned*)&bf3)[3] = 0u;
        f32x4 c3p = (f32x4){0.f, 0.f, 0.f, 0.f};
        c3p = MFMA16(a3h, bf3, c3p);
        // D[row=4hh+i][col=nn] -> pp[w][col][row], valid rows<8 (hh<2), cols<8
        if (nn < 8 && hh < 2)
          *(float4*)(pp + w * 64 + nn * 8 + 4 * hh) =
              make_float4(c3p[0], c3p[1], c3p[2], c3p[3]);
      }
      __syncthreads();   // pp complete

      // ---------- C: ALL waves redundantly — sum partials + fg + RK + z ----------
      {
        float nv = b3r;
        #pragma unroll
        for (int ww = 0; ww < 8; ++ww) nv += pp[ww * 64 + l];
        float4 xa = *(const float4*)(xmp + r * 8);
        float4 xb = *(const float4*)(xmp + r * 8 + 4);
        float Hr  = fmaf(xa.x, 2.f, 50.f),  CAr = fmaf(xa.y, 0.2f, 1.f);
        float CBr = fmaf(xa.z, 0.1f, 0.5f), Tr  = fmaf(xa.w, 4.f, 313.f);
        float Hb  = fmaf(xb.x, 2.f, 50.f),  CAb = fmaf(xb.y, 0.2f, 1.f);
        float CBb = fmaf(xb.z, 0.1f, 0.5f), Tb  = fmaf(xb.w, 4.f, 313.f);
        float F = u0r + 10.f, D = fmaf(u1r, 0.5f, 5.f);
        float Fr = 2.5f * sqrtf(Hr), Fb = 1.5f * sqrtf(Hb);
        float rH = __builtin_amdgcn_rcpf(3.f * Hr);
        float rB = __builtin_amdgcn_rcpf(3.f * Hb);
        float k0 = (F + D - Fr) * (1.f / 6.f);
        float k1 = (F * (6.f - CAr) - D * CAr) * (5.f * rH);
        float k2 = (-(F + D) * CBr) * (10.f * rH);
        float k3 = (F * (320.f - Tr) + D * (300.f - Tr)) * (0.25f * rH) + (5.f / 3.f) * rH;
        float k4 = (Fr - Fb - D) * (1.f / 6.f);
        float k5 = (Fr * (CAr - CAb) + D * CAb) * (5.f * rB);
        float k6 = (Fr * (CBr - CBb) + D * CBb) * (10.f * rB);
        float k7 = Fr * (Tr - Tb) * (0.25f * rB) + (5.f / 3.f) * rB;
        float fgc = (c & 4) ? ((c & 2) ? ((c & 1) ? k7 : k6) : ((c & 1) ? k5 : k4))
                            : ((c & 2) ? ((c & 1) ? k3 : k2) : ((c & 1) ? k1 : k0));
        float kv = fgc + nv;
        float cc;
        if (s == 0)      { kacc = kv;                  cc = fmaf(kv, 0.005f, xg); }
        else if (s == 1) { kacc = fmaf(kv, 2.f, kacc); cc = fmaf(kv, 0.005f, xg); }
        else if (s == 2) { kacc = fmaf(kv, 2.f, kacc); cc = fmaf(kv, 0.01f,  xg); }
        else             { xg = fmaf(kacc + kv, 0.01f / 6.f, xg); cc = xg; }
        xmp[r * 8 + c] = cc;                 // next stage's fg input (private)
        inhp[r * 72 + c] = f2bf(cc);         // next stage's L1 input (private)

        if (s == 0) {            // yp_interp for k2/k3
          inhp[r * 72 +  8 + c] = f2bf(0.5f * (yp0 + yp1));
          inhp[r * 72 + 16 + c] = f2bf(0.5f * (yp1 + yp2));
          inhp[r * 72 + 24 + c] = f2bf(0.5f * (yp2 + yp3));
          inhp[r * 72 + 32 + c] = f2bf(0.5f * (yp3 + yp4));
          inhp[r * 72 + 40 + c] = f2bf(0.5f * (yp4 + xg));
        } else if (s == 2) {     // yp_shift for k4 + rotate (next ypseq)
          inhp[r * 72 +  8 + c] = f2bf(yp1);
          inhp[r * 72 + 16 + c] = f2bf(yp2);
          inhp[r * 72 + 24 + c] = f2bf(yp3);
          inhp[r * 72 + 32 + c] = f2bf(yp4);
          inhp[r * 72 + 40 + c] = f2bf(xg);
          yp0 = yp1; yp1 = yp2; yp2 = yp3; yp3 = yp4; yp4 = xg;
        } else if (s == 3) {     // upseq shift + next-step u
          float tA = __shfl(upA, r * 8 + ((c + 2) & 7));
          float tB = __shfl(upB, r * 8 + ((c >= 6) ? (c - 6) : 0));
          float nu = (c < 6) ? tA : tB;
          upA = nu;
          inhp[r * 72 + 48 + c] = f2bf(nu);
          if (c < 2) {
            float uv = (c == 0) ? u0r : u1r;
            upB = uv;
            inhp[r * 72 + 56 + c] = f2bf(uv);
            if (t < 127)
              inhp[r * 72 + 58 + c] = f2bf(su[r * 260 + 2 * (t + 1) + c]);
          }
        }
      }
      // no barrier: next A reads only private inh; pp-read-vs-write fenced by
      // the h1 barrier of the next stage.
    } // s
  } // t
}

extern "C" void kernel_launch(void* const* d_in, const int* in_sizes, int n_in,
                              void* d_out, int out_size, void* d_ws, size_t ws_size,
                              hipStream_t stream) {
  const float* useq = (const float*)d_in[0];
  const float* xGz0 = (const float*)d_in[1];
  const float* W1   = (const float*)d_in[2];
  const float* b1   = (const float*)d_in[3];
  const float* W2   = (const float*)d_in[4];
  const float* b2   = (const float*)d_in[5];
  const float* W3   = (const float*)d_in[6];
  const float* b3   = (const float*)d_in[7];
  float* out = (float*)d_out;

  size_t lds = (size_t)LDSN * sizeof(float);
  (void)hipFuncSetAttribute((const void*)cstr_rk4_mfma8,
                            hipFuncAttributeMaxDynamicSharedMemorySize, (int)lds);
  hipLaunchKernelGGL(cstr_rk4_mfma8, dim3(2048 / ROWS), dim3(BLOCK), lds, stream,
                     useq, xGz0, W1, b1, W2, b2, W3, b3, out);
}